// Round 5
// baseline (714.239 us; speedup 1.0000x reference)
//
#include <hip/hip_runtime.h>
#include <hip/hip_bf16.h>

using bf16 = __hip_bfloat16;
using short8 = __attribute__((ext_vector_type(8))) short;   // 8 bf16 (4 VGPRs)
using float4v = __attribute__((ext_vector_type(4))) float;  // 4 fp32 acc

#define N_TOK 8192
#define DMODEL 512
#define HDIM 2048
#define NEXP 8
#define NPAIR 16384
#define PAIR_PAD 16512  // NPAIR + 128 slack rows for partial tiles (old 128-tile kernel)
#define NGBLK 2048      // gating blocks (4 tokens / 8 pairs each)

#define ASYNC_CP16(gsrc, ldst)                                                   \
    __builtin_amdgcn_global_load_lds(                                            \
        (const __attribute__((address_space(1))) void*)(gsrc),                   \
        (__attribute__((address_space(3))) void*)(ldst), 16, 0, 0)

typedef __attribute__((address_space(3))) char lds3_t;

#define BAR() asm volatile("s_barrier" ::: "memory")
#define WAIT_VM8() asm volatile("s_waitcnt vmcnt(8)" ::: "memory")
#define WAIT_VM0() asm volatile("s_waitcnt vmcnt(0)" ::: "memory")
#define SBAR() __builtin_amdgcn_sched_barrier(0)
#define WAITL_(n) asm volatile("s_waitcnt lgkmcnt(" #n ")" ::: "memory")
#define WAITL(n) WAITL_(n)
#define DSR(dst, addr, imm) \
    asm volatile("ds_read_b128 %0, %1 offset:%2" : "=v"(dst) : "v"(addr), "i"(imm))

// tanh-approx gelu: x*sigmoid(2u), u = s(x+0.044715x^3).
// max abs err vs exact-erf gelu ~1e-3 -- far below bf16 quantization here.
__device__ __forceinline__ float gelu_fast(float v) {
    float u = v * (0.7978845608f + 0.0356774081f * v * v);
    float t = __expf(-2.0f * u);
    return v * __builtin_amdgcn_rcpf(1.0f + t);
}
__device__ __forceinline__ float bf2f(short s) {
    return __uint_as_float(((unsigned)(unsigned short)s) << 16);
}
__device__ __forceinline__ short f2bf(float f) {
    return (short)__bfloat16_as_ushort(__float2bfloat16(f));
}

// ---------------- x fp32 -> bf16 ----------------
__global__ void cvt_x_k(const float* __restrict__ x, bf16* __restrict__ xb) {
    int i = blockIdx.x * 256 + threadIdx.x;
    if (i >= N_TOK * DMODEL / 4) return;
    const float4 f = *(const float4*)(x + (size_t)i * 4);
    union { ushort u[4]; uint2 v; } r;
    r.u[0] = __bfloat16_as_ushort(__float2bfloat16(f.x));
    r.u[1] = __bfloat16_as_ushort(__float2bfloat16(f.y));
    r.u[2] = __bfloat16_as_ushort(__float2bfloat16(f.z));
    r.u[3] = __bfloat16_as_ushort(__float2bfloat16(f.w));
    *(uint2*)(xb + (size_t)i * 4) = r.v;
}

// ---------------- gating: logits, top-2, softmax ----------------
// R2: no global atomics (16384 same-line atomicAdds serialized ~194us).
// Counts go to a per-block LDS histogram -> plain store to blkc[b][8].
__global__ void gating_k(const float* __restrict__ x, const float* __restrict__ gw,
                         int* __restrict__ tok_idx, float* __restrict__ tok_gate,
                         int* __restrict__ blkc) {
    __shared__ int hist[8];
    if (threadIdx.x < 8) hist[threadIdx.x] = 0;
    __syncthreads();
    int n = blockIdx.x * 4 + (threadIdx.x >> 6);
    int lane = threadIdx.x & 63;
    double acc[NEXP];
#pragma unroll
    for (int e = 0; e < NEXP; e++) acc[e] = 0.0;
    const float* xr = x + (size_t)n * DMODEL;
    for (int d = lane; d < DMODEL; d += 64) {
        float xv = xr[d];
        const float* g = gw + (size_t)d * NEXP;
#pragma unroll
        for (int e = 0; e < NEXP; e++) acc[e] += (double)xv * (double)g[e];
    }
#pragma unroll
    for (int m = 32; m >= 1; m >>= 1)
#pragma unroll
        for (int e = 0; e < NEXP; e++) acc[e] += __shfl_xor(acc[e], m, 64);
    if (lane == 0) {
        double best = acc[0]; int bi = 0;
#pragma unroll
        for (int e = 1; e < NEXP; e++) if (acc[e] > best) { best = acc[e]; bi = e; }
        double best2 = -1e300; int bi2 = 0;
#pragma unroll
        for (int e = 0; e < NEXP; e++) if (e != bi && acc[e] > best2) { best2 = acc[e]; bi2 = e; }
        double t = exp(best2 - best);
        float g0 = (float)(1.0 / (1.0 + t));
        float g1 = (float)(t / (1.0 + t));
        tok_idx[2 * n] = bi;  tok_idx[2 * n + 1] = bi2;
        tok_gate[2 * n] = g0; tok_gate[2 * n + 1] = g1;
        atomicAdd(&hist[bi], 1);   // LDS atomic: block-local, cheap
        atomicAdd(&hist[bi2], 1);
    }
    __syncthreads();
    if (threadIdx.x < 8) blkc[blockIdx.x * 8 + threadIdx.x] = hist[threadIdx.x];
}

// ---------------- per-expert prefix over [NGBLK][8] block counts ----------------
__global__ void scan_k(const int* __restrict__ blkc, int* __restrict__ blkbase,
                       int* __restrict__ offs_g) {
    __shared__ int totals[8];
    const int tid = threadIdx.x;
    const int w = tid >> 6, l = tid & 63;
    int loc[32];
    int s = 0;
#pragma unroll
    for (int i = 0; i < 32; i++) { loc[i] = blkc[(size_t)(l * 32 + i) * 8 + w]; s += loc[i]; }
    int inc = s;
#pragma unroll
    for (int d = 1; d < 64; d <<= 1) {
        int v = __shfl_up(inc, d, 64);
        if (l >= d) inc += v;
    }
    const int excl = inc - s;
    if (l == 63) totals[w] = inc;
    __syncthreads();
    int off = 0;
#pragma unroll
    for (int e = 0; e < 8; e++) off += (e < w) ? totals[e] : 0;
    int run = off + excl;
#pragma unroll
    for (int i = 0; i < 32; i++) { blkbase[(size_t)(l * 32 + i) * 8 + w] = run; run += loc[i]; }
    if (tid < 9) {
        int o = 0;
        for (int e = 0; e < tid; e++) o += totals[e];
        offs_g[tid] = o;
    }
}

// ---------------- atomic-free placement ----------------
__global__ void place_k(const int* __restrict__ tok_idx, const float* __restrict__ tok_gate,
                        const int* __restrict__ blkbase,
                        int* __restrict__ pair_token, float* __restrict__ pair_gate,
                        int* __restrict__ pair_expert, int* __restrict__ pair_of) {
    const int p = blockIdx.x * 256 + threadIdx.x;   // NPAIR = 64*256 exact
    const int lane = threadIdx.x & 63;
    const int e = tok_idx[p];
    const unsigned long long below = (1ull << lane) - 1ull;
    const unsigned long long grpmask = 0xFFull << (lane & 56);
    int rank = 0;
#pragma unroll
    for (int v = 0; v < 8; v++) {
        unsigned long long bal = __ballot(e == v);
        if (e == v) rank = (int)__popcll(bal & grpmask & below);
    }
    const int b = p >> 3;
    const int s = blkbase[b * 8 + e] + rank;
    pair_token[s] = p >> 1;
    pair_gate[s] = tok_gate[p];
    pair_expert[s] = e;
    pair_of[p] = s;
}

// ---- merged weight convert+transpose: fp32 [E][K][N] -> bf16 [E][N][K] ----
__global__ void transpose_all_k(const float* __restrict__ w1, const float* __restrict__ w2,
                                const float* __restrict__ w3, bf16* __restrict__ w1t,
                                bf16* __restrict__ w2t, bf16* __restrict__ w3t) {
    int bid = blockIdx.x;
    int e = bid / 1536, r = bid % 1536;
    const float* W; bf16* Wt; int K, N, kt, nt;
    if (r < 256)       { W = w1; Wt = w1t; K = 512;  N = 2048; kt = r & 7;  nt = r >> 3; }
    else if (r < 1280) { r -= 256;  W = w2; Wt = w2t; K = 2048; N = 2048; kt = r & 31; nt = r >> 5; }
    else               { r -= 1280; W = w3; Wt = w3t; K = 2048; N = 512;  kt = r & 31; nt = r >> 5; }
    const float* Wp = W + (size_t)e * K * N;
    bf16* Wtp = Wt + (size_t)e * K * N;
    int k0 = kt * 64, n0 = nt * 64;
    __shared__ float tile[64][65];
    int t = threadIdx.x;
    int kr = t >> 4, nc = (t & 15) * 4;
#pragma unroll
    for (int j = 0; j < 4; j++) {
        float4 f = *(const float4*)&Wp[(size_t)(k0 + kr + j * 16) * N + n0 + nc];
        tile[kr + j * 16][nc]     = f.x;
        tile[kr + j * 16][nc + 1] = f.y;
        tile[kr + j * 16][nc + 2] = f.z;
        tile[kr + j * 16][nc + 3] = f.w;
    }
    __syncthreads();
    int n = t >> 2, kc = (t & 3) * 4;
#pragma unroll
    for (int j = 0; j < 4; j++) {
        int k = j * 16 + kc;
        union { ushort u[4]; uint2 v; } rr;
#pragma unroll
        for (int i = 0; i < 4; i++)
            rr.u[i] = __bfloat16_as_ushort(__float2bfloat16(tile[k + i][n]));
        *(uint2*)&Wtp[(size_t)(n0 + n) * K + k0 + k] = rr.v;
    }
}

// ---------------- 256x256 8-wave counted-vmcnt grouped GEMM ----------------
// R5: deep per-wave DS queue. R4's issue-1/compute-4/wait pattern kept only 3
// ds_reads in flight per wave; under 8-wave DS contention (~150-290cyc service)
// the wave stalled EVERY row and DS+MFMA serialized (measured 6715 cyc/tile =
// 2048 MFMA + 3070 DS + waits; MfmaUtil 35%). Now: issue all 12 reads at phase
// top (bq0-3, af0-7), then descending counted waits lgkmcnt(7..0) -- row i
// needs exactly the first 5+i reads retired (DS retires in order). DS pipe
// drains ~96 queued reads/CU/phase (~1150cyc) overlapping MFMA (~1024cyc/SIMD).
// Staging: all 8 loads (A+B, tile t+1) at tile top; vmcnt(8) retires exactly
// tile t's 8 (invariant: 8 outstanding at every tile top). sched_barrier(0)
// after every wait per rule 18.
template <int KD, int ND, int EPI>
__launch_bounds__(512, 2)
__global__ void gemm256_k(const bf16* __restrict__ Abase, const bf16* __restrict__ Bt,
                          const int* __restrict__ row_map, const int* __restrict__ offs,
                          bf16* __restrict__ Hout, float* __restrict__ Yout,
                          const float* __restrict__ pair_gate) {
    const int e = blockIdx.z;
    const int off = offs[e];
    const int cnt = offs[e + 1] - off;
    const int m0 = blockIdx.y * 256;
    if (m0 >= cnt) return;
    const int n0 = blockIdx.x * 256;

    __shared__ __align__(16) char LDS[131072];

    const int tid = threadIdx.x;
    const int lane = tid & 63, w = tid >> 6;       // 8 waves
    const int wm = w >> 2, wn = w & 3;             // 2(M) x 4(N); per-wave 128x64
    const int c16 = lane & 15, q = lane >> 4;
    const bf16* Bp = Bt + (size_t)e * ND * KD;

    // ---- ds_read bases (per-lane, swizzled) ----
    const unsigned s0 = (unsigned)((q ^ (lane & 7)) << 4);
    const unsigned a_rd = (unsigned)((wm * 128 + c16) * 128) + s0;
    const unsigned b_rd = 32768u + (unsigned)((wn * 64 + c16) * 128) + s0;

    // ---- staging setup: wave w owns chunks w*4+j (8 rows each) ----
    const int dstA = w * 4096;                               // (w*4)*1024
    const int srow = w * 32 + (lane >> 3);                   // +j*8
    const int kperm = ((lane & 7) ^ (lane >> 3)) << 3;       // elem offset in row
    const bf16* pa[4]; const bf16* pb[4];
#pragma unroll
    for (int j = 0; j < 4; j++) {
        int rl = m0 + srow + j * 8;
        if (rl > cnt - 1) rl = cnt - 1;                      // clamp: no pad reads
        size_t ga = row_map ? (size_t)row_map[off + rl] : (size_t)(off + rl);
        pa[j] = Abase + ga * KD + kperm;
        pb[j] = Bp + (size_t)(n0 + srow + j * 8) * KD + kperm;
    }

    float4v acc[8][4];
#pragma unroll
    for (int mi = 0; mi < 8; mi++)
#pragma unroll
        for (int ni = 0; ni < 4; ni++) acc[mi][ni] = (float4v){0.f, 0.f, 0.f, 0.f};

    lds3_t* L3 = (lds3_t*)LDS;
    constexpr int NT = KD / 64;

#define MFMA_ROW(mi_)                                                     \
    _Pragma("unroll") for (int ni = 0; ni < 4; ni++)                      \
        acc[mi_][ni] = __builtin_amdgcn_mfma_f32_16x16x32_bf16(           \
            af[mi_], bq[ni], acc[mi_][ni], 0, 0, 0);

#define PHASE_PIPE(AB, BB)                                                \
    DSR(bq[0], BB, 0);       DSR(bq[1], BB, 2048);                        \
    DSR(bq[2], BB, 4096);    DSR(bq[3], BB, 6144);                        \
    DSR(af[0], AB, 0);       DSR(af[1], AB, 2048);                        \
    DSR(af[2], AB, 4096);    DSR(af[3], AB, 6144);                        \
    DSR(af[4], AB, 8192);    DSR(af[5], AB, 10240);                       \
    DSR(af[6], AB, 12288);   DSR(af[7], AB, 14336);                       \
    WAITL(7); SBAR();                                                     \
    __builtin_amdgcn_s_setprio(1);                                        \
    MFMA_ROW(0); WAITL(6); SBAR();                                        \
    MFMA_ROW(1); WAITL(5); SBAR();                                        \
    MFMA_ROW(2); WAITL(4); SBAR();                                        \
    MFMA_ROW(3); WAITL(3); SBAR();                                        \
    MFMA_ROW(4); WAITL(2); SBAR();                                        \
    MFMA_ROW(5); WAITL(1); SBAR();                                        \
    MFMA_ROW(6); WAITL(0); SBAR();                                        \
    MFMA_ROW(7);                                                          \
    __builtin_amdgcn_s_setprio(0);                                        \
    SBAR();

    // prologue: stage tile 0 into buf0 (A then B; 8 loads outstanding)
#pragma unroll
    for (int j = 0; j < 4; j++) { ASYNC_CP16(pa[j], LDS + dstA + j * 1024); pa[j] += 64; }
#pragma unroll
    for (int j = 0; j < 4; j++) { ASYNC_CP16(pb[j], LDS + 32768 + dstA + j * 1024); pb[j] += 64; }
    SBAR();

    unsigned cur = 0;
    for (int tt = 0; tt < NT; ++tt) {
        short8 af[8], bq[4];
        const bool pf = (tt + 1 < NT);
        BAR();  // all waves done reading buf[t-1] -> safe to overwrite it
        if (pf) {
            const unsigned nb = cur ^ 65536u;
            SBAR();
#pragma unroll
            for (int j = 0; j < 4; j++) { ASYNC_CP16(pa[j], LDS + nb + dstA + j * 1024); pa[j] += 64; }
#pragma unroll
            for (int j = 0; j < 4; j++) { ASYNC_CP16(pb[j], LDS + nb + 32768 + dstA + j * 1024); pb[j] += 64; }
            SBAR();
            WAIT_VM8();  // retire exactly tile t's 8 loads; keep t+1's 8 in flight
        } else {
            WAIT_VM0();
        }
        SBAR();
        BAR();  // tile t data visible to all waves
        {
            lds3_t* AB = L3 + (a_rd + cur);
            lds3_t* BB = L3 + (b_rd + cur);
            PHASE_PIPE(AB, BB);
        }
        {
            lds3_t* AB = L3 + ((a_rd + cur) ^ 0x40u);
            lds3_t* BB = L3 + ((b_rd + cur) ^ 0x40u);
            PHASE_PIPE(AB, BB);
        }
        cur ^= 65536u;
    }
#undef PHASE_PIPE
#undef MFMA_ROW

    // epilogue: D layout col = lane&15, row = (lane>>4)*4 + reg
#pragma unroll
    for (int mi = 0; mi < 8; mi++)
#pragma unroll
        for (int reg = 0; reg < 4; reg++) {
            int row = wm * 128 + mi * 16 + q * 4 + reg;
            if (m0 + row < cnt) {
                size_t gp = (size_t)(off + m0 + row);
                if (EPI == 0) {
#pragma unroll
                    for (int ni = 0; ni < 4; ni++) {
                        int col = n0 + wn * 64 + ni * 16 + c16;
                        Hout[gp * ND + col] = __float2bfloat16(gelu_fast(acc[mi][ni][reg]));
                    }
                } else {
                    float gt = pair_gate[gp];
#pragma unroll
                    for (int ni = 0; ni < 4; ni++) {
                        int col = n0 + wn * 64 + ni * 16 + c16;
                        Yout[gp * ND + col] = acc[mi][ni][reg] * gt;
                    }
                }
            }
        }
}

// ---------------- 128x128 grouped GEMM (kept for stage 3, N=512) ----------------
template <int KD, int ND, int EPI>
__launch_bounds__(256, 2)
__global__ void gemm_moe_k(const bf16* __restrict__ Abase, const bf16* __restrict__ Bt,
                           const int* __restrict__ row_map, const int* __restrict__ offs,
                           bf16* __restrict__ Hout, float* __restrict__ Yout,
                           const float* __restrict__ pair_gate) {
    const int e = blockIdx.z;
    const int off = offs[e];
    const int cnt = offs[e + 1] - off;
    const int m0 = blockIdx.y * 128;
    if (m0 >= cnt) return;
    const int n0 = blockIdx.x * 128;

    __shared__ alignas(16) bf16 As[128 * 32];
    __shared__ alignas(16) bf16 Bs[128 * 32];

    const int t = threadIdx.x;
    const int lane = t & 63, w = t >> 6;
    const bf16* Bp = Bt + (size_t)e * ND * KD;

    const int i0 = 2 * w, i1 = 2 * w + 1;
    const int ar0 = i0 * 16 + (lane >> 2);
    const int ar1 = i1 * 16 + (lane >> 2);
    const int kc = (lane & 3) * 8;

    size_t ga0, ga1;
    if (row_map) {
        ga0 = (m0 + ar0 < cnt) ? (size_t)row_map[off + m0 + ar0] : 0;
        ga1 = (m0 + ar1 < cnt) ? (size_t)row_map[off + m0 + ar1] : 0;
    } else {
        ga0 = (size_t)(off + m0 + ar0);
        ga1 = (size_t)(off + m0 + ar1);
    }
    const bf16* Ap0 = Abase + ga0 * KD + kc;
    const bf16* Ap1 = Abase + ga1 * KD + kc;
    const bf16* Bq0 = Bp + (size_t)(n0 + ar0) * KD + kc;
    const bf16* Bq1 = Bp + (size_t)(n0 + ar1) * KD + kc;

    bf16* lA0 = As + i0 * 512;
    bf16* lA1 = As + i1 * 512;
    bf16* lB0 = Bs + i0 * 512;
    bf16* lB1 = Bs + i1 * 512;

    const int wm = (w >> 1) * 64, wn = (w & 1) * 64;
    const int q = lane >> 4, c16 = lane & 15;

    float4v acc[4][4];
#pragma unroll
    for (int mi = 0; mi < 4; mi++)
#pragma unroll
        for (int ni = 0; ni < 4; ni++) acc[mi][ni] = (float4v){0.f, 0.f, 0.f, 0.f};

    for (int k0 = 0; k0 < KD; k0 += 32) {
        ASYNC_CP16(Ap0 + k0, lA0);
        ASYNC_CP16(Ap1 + k0, lA1);
        ASYNC_CP16(Bq0 + k0, lB0);
        ASYNC_CP16(Bq1 + k0, lB1);
        __syncthreads();
        short8 af[4], bfr[4];
#pragma unroll
        for (int mi = 0; mi < 4; mi++)
            af[mi] = *(const short8*)&As[(wm + mi * 16 + c16) * 32 + q * 8];
#pragma unroll
        for (int ni = 0; ni < 4; ni++)
            bfr[ni] = *(const short8*)&Bs[(wn + ni * 16 + c16) * 32 + q * 8];
#pragma unroll
        for (int mi = 0; mi < 4; mi++)
#pragma unroll
            for (int ni = 0; ni < 4; ni++)
                acc[mi][ni] = __builtin_amdgcn_mfma_f32_16x16x32_bf16(
                    af[mi], bfr[ni], acc[mi][ni], 0, 0, 0);
        __syncthreads();
    }

#pragma unroll
    for (int mi = 0; mi < 4; mi++)
#pragma unroll
        for (int reg = 0; reg < 4; reg++) {
            int row = wm + mi * 16 + q * 4 + reg;
            if (m0 + row < cnt) {
                size_t gp = (size_t)(off + m0 + row);
                if (EPI == 0) {
#pragma unroll
                    for (int ni = 0; ni < 4; ni++) {
                        int col = n0 + wn + ni * 16 + c16;
                        Hout[gp * ND + col] = __float2bfloat16(gelu_fast(acc[mi][ni][reg]));
                    }
                } else {
                    float gt = pair_gate[gp];
#pragma unroll
                    for (int ni = 0; ni < 4; ni++) {
                        int col = n0 + wn + ni * 16 + c16;
                        Yout[gp * ND + col] = acc[mi][ni][reg] * gt;
                    }
                }
            }
        }
}

// ---------------- rmsnorm (ADD=1: also add H1n residual), in place, vectorized ----------------
template <int ADD>
__global__ void rmsnorm_k(bf16* __restrict__ H, const bf16* __restrict__ H1n,
                          const float* __restrict__ nw, const int* __restrict__ pair_expert) {
    int p = blockIdx.x;
    int t = threadIdx.x;
    bf16* row = H + (size_t)p * HDIM + t * 8;
    short8 hv = *(const short8*)row;
    float v[8];
    float ss = 0.f;
#pragma unroll
    for (int i = 0; i < 8; i++) {
        v[i] = bf2f(hv[i]);
        ss += v[i] * v[i];
    }
#pragma unroll
    for (int m = 32; m >= 1; m >>= 1) ss += __shfl_xor(ss, m, 64);
    __shared__ float s4[4];
    int wv = t >> 6, lane = t & 63;
    if (lane == 0) s4[wv] = ss;
    __syncthreads();
    ss = s4[0] + s4[1] + s4[2] + s4[3];
    float scale = rsqrtf(ss / (float)HDIM + 1e-6f);
    int e = pair_expert[p];
    const float* nr = nw + (size_t)e * HDIM + t * 8;
    float4 na = *(const float4*)nr;
    float4 nb = *(const float4*)(nr + 4);
    float nv[8] = {na.x, na.y, na.z, na.w, nb.x, nb.y, nb.z, nb.w};
    short8 res;
    short8 r8;
    if (ADD) r8 = *(const short8*)(H1n + (size_t)p * HDIM + t * 8);
#pragma unroll
    for (int i = 0; i < 8; i++) {
        float o = v[i] * scale * nv[i];
        if (ADD) o += bf2f(r8[i]);
        res[i] = f2bf(o);
    }
    *(short8*)row = res;
}

// ---------------- combine two pair outputs per token ----------------
__global__ void combine_k(const float* __restrict__ y, const int* __restrict__ pair_of,
                          float* __restrict__ out) {
    int i = blockIdx.x * 256 + threadIdx.x;
    if (i >= N_TOK * DMODEL / 4) return;
    int n = i >> 7, d4 = (i & 127) << 2;
    int p0 = pair_of[2 * n], p1 = pair_of[2 * n + 1];
    const float4 a = *(const float4*)(y + (size_t)p0 * DMODEL + d4);
    const float4 b = *(const float4*)(y + (size_t)p1 * DMODEL + d4);
    float4 r;
    r.x = a.x + b.x; r.y = a.y + b.y; r.z = a.z + b.z; r.w = a.w + b.w;
    *(float4*)(out + (size_t)n * DMODEL + d4) = r;
}

extern "C" void kernel_launch(void* const* d_in, const int* in_sizes, int n_in,
                              void* d_out, int out_size, void* d_ws, size_t ws_size,
                              hipStream_t stream) {
    const float* x  = (const float*)d_in[0];
    const float* gw = (const float*)d_in[1];
    const float* w1 = (const float*)d_in[2];
    const float* w2 = (const float*)d_in[3];
    const float* w3 = (const float*)d_in[4];
    const float* n1 = (const float*)d_in[5];
    const float* n2 = (const float*)d_in[6];
    float* out = (float*)d_out;

    char* wsp = (char*)d_ws;
    size_t cur = 0;
    auto take = [&](size_t bytes) -> void* {
        void* p = wsp + cur;
        cur += (bytes + 255) & ~(size_t)255;
        return p;
    };
    bf16* xb  = (bf16*)take((size_t)N_TOK * DMODEL * 2);
    bf16* w1t = (bf16*)take((size_t)NEXP * DMODEL * HDIM * 2);
    bf16* w2t = (bf16*)take((size_t)NEXP * HDIM * HDIM * 2);
    bf16* w3t = (bf16*)take((size_t)NEXP * HDIM * DMODEL * 2);
    bf16* h1  = (bf16*)take((size_t)PAIR_PAD * HDIM * 2);
    bf16* h2  = (bf16*)take((size_t)PAIR_PAD * HDIM * 2);
    float* y  = (float*)take((size_t)PAIR_PAD * DMODEL * 4);
    int* tok_idx     = (int*)take((size_t)NPAIR * 4);
    float* tok_gate  = (float*)take((size_t)NPAIR * 4);
    int* pair_token  = (int*)take((size_t)PAIR_PAD * 4);
    float* pair_gate = (float*)take((size_t)PAIR_PAD * 4);
    int* pair_expert = (int*)take((size_t)PAIR_PAD * 4);
    int* pair_of     = (int*)take((size_t)NPAIR * 4);
    int* blkc    = (int*)take((size_t)NGBLK * 8 * 4);
    int* blkbase = (int*)take((size_t)NGBLK * 8 * 4);
    int* offs    = (int*)take((NEXP + 1) * 4);

    cvt_x_k<<<N_TOK * DMODEL / 4 / 256, 256, 0, stream>>>(x, xb);
    gating_k<<<NGBLK, 256, 0, stream>>>(x, gw, tok_idx, tok_gate, blkc);
    scan_k<<<1, 512, 0, stream>>>(blkc, blkbase, offs);
    place_k<<<NPAIR / 256, 256, 0, stream>>>(tok_idx, tok_gate, blkbase,
                                             pair_token, pair_gate, pair_expert, pair_of);

    transpose_all_k<<<NEXP * 1536, 256, 0, stream>>>(w1, w2, w3, w1t, w2t, w3t);

    // stage 1: h1 = gelu(x @ w1)   (256x256 counted-vmcnt kernel)
    gemm256_k<DMODEL, HDIM, 0><<<dim3(HDIM / 256, 64, NEXP), 512, 0, stream>>>(
        xb, w1t, pair_token, offs, h1, nullptr, nullptr);
    rmsnorm_k<0><<<NPAIR, 256, 0, stream>>>(h1, nullptr, n1, pair_expert);

    // stage 2: h2 = gelu(h1n @ w2)
    gemm256_k<HDIM, HDIM, 0><<<dim3(HDIM / 256, 64, NEXP), 512, 0, stream>>>(
        h1, w2t, nullptr, offs, h2, nullptr, nullptr);
    rmsnorm_k<1><<<NPAIR, 256, 0, stream>>>(h2, h1, n2, pair_expert);

    // stage 3: y = gate * ((h2n + h1n) @ w3)  (N=512: 256-wide tiles would idle
    // half the CUs -- keep the 128x128 kernel here)
    gemm_moe_k<HDIM, DMODEL, 1><<<dim3(DMODEL / 128, 64, NEXP), 256, 0, stream>>>(
        h2, w3t, nullptr, offs, nullptr, y, pair_gate);

    combine_k<<<N_TOK * DMODEL / 4 / 256, 256, 0, stream>>>(y, pair_of, out);
}

// Round 6
// 652.978 us; speedup vs baseline: 1.0938x; 1.0938x over previous
//
#include <hip/hip_runtime.h>
#include <hip/hip_bf16.h>

using bf16 = __hip_bfloat16;
using short8 = __attribute__((ext_vector_type(8))) short;   // 8 bf16 (4 VGPRs)
using float4v = __attribute__((ext_vector_type(4))) float;  // 4 fp32 acc

#define N_TOK 8192
#define DMODEL 512
#define HDIM 2048
#define NEXP 8
#define NPAIR 16384
#define PAIR_PAD 16512
#define NGBLK 2048      // gating blocks (4 tokens / 8 pairs each)

#define ASYNC_CP16(gsrc, ldst)                                                   \
    __builtin_amdgcn_global_load_lds(                                            \
        (const __attribute__((address_space(1))) void*)(gsrc),                   \
        (__attribute__((address_space(3))) void*)(ldst), 16, 0, 0)

typedef __attribute__((address_space(3))) char lds3_t;

#define BAR() asm volatile("s_barrier" ::: "memory")
#define WAIT_VM4() asm volatile("s_waitcnt vmcnt(4)" ::: "memory")
#define WAIT_VM0() asm volatile("s_waitcnt vmcnt(0)" ::: "memory")
#define SBAR() __builtin_amdgcn_sched_barrier(0)
#define WAITL_(n) asm volatile("s_waitcnt lgkmcnt(" #n ")" ::: "memory")
#define WAITL(n) WAITL_(n)
#define DSR(dst, addr, imm) \
    asm volatile("ds_read_b128 %0, %1 offset:%2" : "=v"(dst) : "v"(addr), "i"(imm))

// tanh-approx gelu: x*sigmoid(2u), u = s(x+0.044715x^3).
__device__ __forceinline__ float gelu_fast(float v) {
    float u = v * (0.7978845608f + 0.0356774081f * v * v);
    float t = __expf(-2.0f * u);
    return v * __builtin_amdgcn_rcpf(1.0f + t);
}
__device__ __forceinline__ float bf2f(short s) {
    return __uint_as_float(((unsigned)(unsigned short)s) << 16);
}
__device__ __forceinline__ short f2bf(float f) {
    return (short)__bfloat16_as_ushort(__float2bfloat16(f));
}

// ---------------- x fp32 -> bf16 ----------------
__global__ void cvt_x_k(const float* __restrict__ x, bf16* __restrict__ xb) {
    int i = blockIdx.x * 256 + threadIdx.x;
    if (i >= N_TOK * DMODEL / 4) return;
    const float4 f = *(const float4*)(x + (size_t)i * 4);
    union { ushort u[4]; uint2 v; } r;
    r.u[0] = __bfloat16_as_ushort(__float2bfloat16(f.x));
    r.u[1] = __bfloat16_as_ushort(__float2bfloat16(f.y));
    r.u[2] = __bfloat16_as_ushort(__float2bfloat16(f.z));
    r.u[3] = __bfloat16_as_ushort(__float2bfloat16(f.w));
    *(uint2*)(xb + (size_t)i * 4) = r.v;
}

// ---------------- gating: logits, top-2, softmax ----------------
// R2: no global atomics (16384 same-line atomicAdds serialized ~194us).
__global__ void gating_k(const float* __restrict__ x, const float* __restrict__ gw,
                         int* __restrict__ tok_idx, float* __restrict__ tok_gate,
                         int* __restrict__ blkc) {
    __shared__ int hist[8];
    if (threadIdx.x < 8) hist[threadIdx.x] = 0;
    __syncthreads();
    int n = blockIdx.x * 4 + (threadIdx.x >> 6);
    int lane = threadIdx.x & 63;
    double acc[NEXP];
#pragma unroll
    for (int e = 0; e < NEXP; e++) acc[e] = 0.0;
    const float* xr = x + (size_t)n * DMODEL;
    for (int d = lane; d < DMODEL; d += 64) {
        float xv = xr[d];
        const float* g = gw + (size_t)d * NEXP;
#pragma unroll
        for (int e = 0; e < NEXP; e++) acc[e] += (double)xv * (double)g[e];
    }
#pragma unroll
    for (int m = 32; m >= 1; m >>= 1)
#pragma unroll
        for (int e = 0; e < NEXP; e++) acc[e] += __shfl_xor(acc[e], m, 64);
    if (lane == 0) {
        double best = acc[0]; int bi = 0;
#pragma unroll
        for (int e = 1; e < NEXP; e++) if (acc[e] > best) { best = acc[e]; bi = e; }
        double best2 = -1e300; int bi2 = 0;
#pragma unroll
        for (int e = 0; e < NEXP; e++) if (e != bi && acc[e] > best2) { best2 = acc[e]; bi2 = e; }
        double t = exp(best2 - best);
        float g0 = (float)(1.0 / (1.0 + t));
        float g1 = (float)(t / (1.0 + t));
        tok_idx[2 * n] = bi;  tok_idx[2 * n + 1] = bi2;
        tok_gate[2 * n] = g0; tok_gate[2 * n + 1] = g1;
        atomicAdd(&hist[bi], 1);   // LDS atomic: block-local, cheap
        atomicAdd(&hist[bi2], 1);
    }
    __syncthreads();
    if (threadIdx.x < 8) blkc[blockIdx.x * 8 + threadIdx.x] = hist[threadIdx.x];
}

// ---------------- per-expert prefix over [NGBLK][8] block counts ----------------
__global__ void scan_k(const int* __restrict__ blkc, int* __restrict__ blkbase,
                       int* __restrict__ offs_g) {
    __shared__ int totals[8];
    const int tid = threadIdx.x;
    const int w = tid >> 6, l = tid & 63;
    int loc[32];
    int s = 0;
#pragma unroll
    for (int i = 0; i < 32; i++) { loc[i] = blkc[(size_t)(l * 32 + i) * 8 + w]; s += loc[i]; }
    int inc = s;
#pragma unroll
    for (int d = 1; d < 64; d <<= 1) {
        int v = __shfl_up(inc, d, 64);
        if (l >= d) inc += v;
    }
    const int excl = inc - s;
    if (l == 63) totals[w] = inc;
    __syncthreads();
    int off = 0;
#pragma unroll
    for (int e = 0; e < 8; e++) off += (e < w) ? totals[e] : 0;
    int run = off + excl;
#pragma unroll
    for (int i = 0; i < 32; i++) { blkbase[(size_t)(l * 32 + i) * 8 + w] = run; run += loc[i]; }
    if (tid < 9) {
        int o = 0;
        for (int e = 0; e < tid; e++) o += totals[e];
        offs_g[tid] = o;
    }
}

// ---------------- atomic-free placement ----------------
__global__ void place_k(const int* __restrict__ tok_idx, const float* __restrict__ tok_gate,
                        const int* __restrict__ blkbase,
                        int* __restrict__ pair_token, float* __restrict__ pair_gate,
                        int* __restrict__ pair_expert, int* __restrict__ pair_of) {
    const int p = blockIdx.x * 256 + threadIdx.x;   // NPAIR = 64*256 exact
    const int lane = threadIdx.x & 63;
    const int e = tok_idx[p];
    const unsigned long long below = (1ull << lane) - 1ull;
    const unsigned long long grpmask = 0xFFull << (lane & 56);
    int rank = 0;
#pragma unroll
    for (int v = 0; v < 8; v++) {
        unsigned long long bal = __ballot(e == v);
        if (e == v) rank = (int)__popcll(bal & grpmask & below);
    }
    const int b = p >> 3;
    const int s = blkbase[b * 8 + e] + rank;
    pair_token[s] = p >> 1;
    pair_gate[s] = tok_gate[p];
    pair_expert[s] = e;
    pair_of[p] = s;
}

// ---- merged weight convert+transpose: fp32 [E][K][N] -> bf16 [E][N][K] ----
__global__ void transpose_all_k(const float* __restrict__ w1, const float* __restrict__ w2,
                                const float* __restrict__ w3, bf16* __restrict__ w1t,
                                bf16* __restrict__ w2t, bf16* __restrict__ w3t) {
    int bid = blockIdx.x;
    int e = bid / 1536, r = bid % 1536;
    const float* W; bf16* Wt; int K, N, kt, nt;
    if (r < 256)       { W = w1; Wt = w1t; K = 512;  N = 2048; kt = r & 7;  nt = r >> 3; }
    else if (r < 1280) { r -= 256;  W = w2; Wt = w2t; K = 2048; N = 2048; kt = r & 31; nt = r >> 5; }
    else               { r -= 1280; W = w3; Wt = w3t; K = 2048; N = 512;  kt = r & 31; nt = r >> 5; }
    const float* Wp = W + (size_t)e * K * N;
    bf16* Wtp = Wt + (size_t)e * K * N;
    int k0 = kt * 64, n0 = nt * 64;
    __shared__ float tile[64][65];
    int t = threadIdx.x;
    int kr = t >> 4, nc = (t & 15) * 4;
#pragma unroll
    for (int j = 0; j < 4; j++) {
        float4 f = *(const float4*)&Wp[(size_t)(k0 + kr + j * 16) * N + n0 + nc];
        tile[kr + j * 16][nc]     = f.x;
        tile[kr + j * 16][nc + 1] = f.y;
        tile[kr + j * 16][nc + 2] = f.z;
        tile[kr + j * 16][nc + 3] = f.w;
    }
    __syncthreads();
    int n = t >> 2, kc = (t & 3) * 4;
#pragma unroll
    for (int j = 0; j < 4; j++) {
        int k = j * 16 + kc;
        union { ushort u[4]; uint2 v; } rr;
#pragma unroll
        for (int i = 0; i < 4; i++)
            rr.u[i] = __bfloat16_as_ushort(__float2bfloat16(tile[k + i][n]));
        *(uint2*)&Wtp[(size_t)(n0 + n) * K + k0 + k] = rr.v;
    }
}

// ---------------- 256x256 8-wave counted-vmcnt grouped GEMM ----------------
// R6: GEMM inner loop reverted to R4 exactly (best measured; R5's deep-queue
// regressed and was confounded).  NEW this round: XCD-chunked block mapping.
// Evidence: staged bytes = 512blk x 32tile x 64KB = 1.07GB/dispatch, FETCH
// 300MB (2.2x the 134MB ideal); per-CU staging 64KB/tile at ~9-10B/cyc = the
// measured 6715 cyc/tile, while MFMA needs only 2483 -> staging-BW bound below
// L2, which is why R3/R4/R5 schedules all landed at MfmaUtil 31-36%.
// Mapping (T1): 1D grid, e = bid&7 (expert -> XCD, 8<->8), j = bid>>3,
// mb = j/NB, nb = j%NB.  Co-resident blocks on one XCD become a 4m x 8n window
// of ONE expert: shared A-panels (x8 reuse) + B-panels (x4) in that XCD's L2.
template <int KD, int ND, int EPI>
__launch_bounds__(512, 2)
__global__ void gemm256_k(const bf16* __restrict__ Abase, const bf16* __restrict__ Bt,
                          const int* __restrict__ row_map, const int* __restrict__ offs,
                          bf16* __restrict__ Hout, float* __restrict__ Yout,
                          const float* __restrict__ pair_gate) {
    constexpr int NB = ND / 256;
    const int bid = blockIdx.x;
    const int e = bid & 7;           // XCD-chunk: expert e -> XCD e
    const int j = bid >> 3;
    const int mb = j / NB, nb = j % NB;
    const int off = offs[e];
    const int cnt = offs[e + 1] - off;
    const int m0 = mb * 256;
    if (m0 >= cnt) return;
    const int n0 = nb * 256;

    __shared__ __align__(16) char LDS[131072];

    const int tid = threadIdx.x;
    const int lane = tid & 63, w = tid >> 6;       // 8 waves
    const int wm = w >> 2, wn = w & 3;             // 2(M) x 4(N); per-wave 128x64
    const int c16 = lane & 15, q = lane >> 4;
    const bf16* Bp = Bt + (size_t)e * ND * KD;

    // ---- ds_read bases (per-lane, swizzled) ----
    const unsigned s0 = (unsigned)((q ^ (lane & 7)) << 4);
    const unsigned a_rd = (unsigned)((wm * 128 + c16) * 128) + s0;
    const unsigned b_rd = 32768u + (unsigned)((wn * 64 + c16) * 128) + s0;

    // ---- staging setup: wave w owns chunks w*4+j (8 rows each) ----
    const int dstA = w * 4096;                               // (w*4)*1024
    const int srow = w * 32 + (lane >> 3);                   // +j*8
    const int kperm = ((lane & 7) ^ (lane >> 3)) << 3;       // elem offset in row
    const bf16* pa[4]; const bf16* pb[4];
#pragma unroll
    for (int jj = 0; jj < 4; jj++) {
        int rl = m0 + srow + jj * 8;
        if (rl > cnt - 1) rl = cnt - 1;                      // clamp: no pad reads
        size_t ga = row_map ? (size_t)row_map[off + rl] : (size_t)(off + rl);
        pa[jj] = Abase + ga * KD + kperm;
        pb[jj] = Bp + (size_t)(n0 + srow + jj * 8) * KD + kperm;
    }

    float4v acc[8][4];
#pragma unroll
    for (int mi = 0; mi < 8; mi++)
#pragma unroll
        for (int ni = 0; ni < 4; ni++) acc[mi][ni] = (float4v){0.f, 0.f, 0.f, 0.f};

    lds3_t* L3 = (lds3_t*)LDS;
    constexpr int NT = KD / 64;

#define MFMA_ROW(mi_)                                                     \
    _Pragma("unroll") for (int ni = 0; ni < 4; ni++)                      \
        acc[mi_][ni] = __builtin_amdgcn_mfma_f32_16x16x32_bf16(           \
            af[mi_], bq[ni], acc[mi_][ni], 0, 0, 0);

#define PHASE_PIPE(AB, BB)                                                \
    DSR(bq[0], BB, 0);       DSR(bq[1], BB, 2048);                        \
    DSR(bq[2], BB, 4096);    DSR(bq[3], BB, 6144);                        \
    DSR(af[0], AB, 0);       DSR(af[1], AB, 2048);                        \
    DSR(af[2], AB, 4096);                                                 \
    WAITL(2); SBAR();                                                     \
    __builtin_amdgcn_s_setprio(1);                                        \
    DSR(af[3], AB, 6144);   MFMA_ROW(0); WAITL(2); SBAR();                \
    DSR(af[4], AB, 8192);   MFMA_ROW(1); WAITL(2); SBAR();                \
    DSR(af[5], AB, 10240);  MFMA_ROW(2); WAITL(2); SBAR();                \
    DSR(af[6], AB, 12288);  MFMA_ROW(3); WAITL(2); SBAR();                \
    DSR(af[7], AB, 14336);  MFMA_ROW(4); WAITL(2); SBAR();                \
    MFMA_ROW(5); WAITL(1); SBAR();                                        \
    MFMA_ROW(6); WAITL(0); SBAR();                                        \
    MFMA_ROW(7);                                                          \
    __builtin_amdgcn_s_setprio(0);                                        \
    SBAR();

    // prologue: stage tile 0 into buf0 (A then B; 8 loads outstanding)
#pragma unroll
    for (int jj = 0; jj < 4; jj++) { ASYNC_CP16(pa[jj], LDS + dstA + jj * 1024); pa[jj] += 64; }
#pragma unroll
    for (int jj = 0; jj < 4; jj++) { ASYNC_CP16(pb[jj], LDS + 32768 + dstA + jj * 1024); pb[jj] += 64; }
    SBAR();

    unsigned cur = 0;
    for (int tt = 0; tt < NT; ++tt) {
        short8 af[8], bq[4];
        const bool pf = (tt + 1 < NT);
        // ---- phase k0 ----
        BAR();  // all waves done reading buf[t-1] -> safe to overwrite it
        if (pf) {
            const unsigned nbuf = cur ^ 65536u;
            SBAR();
#pragma unroll
            for (int jj = 0; jj < 4; jj++) { ASYNC_CP16(pa[jj], LDS + nbuf + dstA + jj * 1024); pa[jj] += 64; }
            SBAR();
            WAIT_VM4();  // retire tile t's 8 loads; keep the 4 just issued in flight
        } else {
            WAIT_VM0();
        }
        SBAR();
        BAR();  // tile t data visible to all waves
        {
            lds3_t* AB = L3 + (a_rd + cur);
            lds3_t* BB = L3 + (b_rd + cur);
            PHASE_PIPE(AB, BB);
        }
        // ---- phase k1 ----
        if (pf) {
            const unsigned nbuf = cur ^ 65536u;
            SBAR();
#pragma unroll
            for (int jj = 0; jj < 4; jj++) { ASYNC_CP16(pb[jj], LDS + nbuf + 32768 + dstA + jj * 1024); pb[jj] += 64; }
            SBAR();
        }
        {
            lds3_t* AB = L3 + ((a_rd + cur) ^ 0x40u);
            lds3_t* BB = L3 + ((b_rd + cur) ^ 0x40u);
            PHASE_PIPE(AB, BB);
        }
        cur ^= 65536u;
    }
#undef PHASE_PIPE
#undef MFMA_ROW

    // epilogue: D layout col = lane&15, row = (lane>>4)*4 + reg
#pragma unroll
    for (int mi = 0; mi < 8; mi++)
#pragma unroll
        for (int reg = 0; reg < 4; reg++) {
            int row = wm * 128 + mi * 16 + q * 4 + reg;
            if (m0 + row < cnt) {
                size_t gp = (size_t)(off + m0 + row);
                if (EPI == 0) {
#pragma unroll
                    for (int ni = 0; ni < 4; ni++) {
                        int col = n0 + wn * 64 + ni * 16 + c16;
                        Hout[gp * ND + col] = __float2bfloat16(gelu_fast(acc[mi][ni][reg]));
                    }
                } else {
                    float gt = pair_gate[gp];
#pragma unroll
                    for (int ni = 0; ni < 4; ni++) {
                        int col = n0 + wn * 64 + ni * 16 + c16;
                        Yout[gp * ND + col] = acc[mi][ni][reg] * gt;
                    }
                }
            }
        }
}

// ---------------- 128x128 grouped GEMM (stage 3, N=512; XCD-chunked 1D grid) ----
template <int KD, int ND, int EPI>
__launch_bounds__(256, 2)
__global__ void gemm_moe_k(const bf16* __restrict__ Abase, const bf16* __restrict__ Bt,
                           const int* __restrict__ row_map, const int* __restrict__ offs,
                           bf16* __restrict__ Hout, float* __restrict__ Yout,
                           const float* __restrict__ pair_gate) {
    constexpr int NB = ND / 128;
    const int bid = blockIdx.x;
    const int e = bid & 7;
    const int j = bid >> 3;
    const int mb = j / NB, nb = j % NB;
    const int off = offs[e];
    const int cnt = offs[e + 1] - off;
    const int m0 = mb * 128;
    if (m0 >= cnt) return;
    const int n0 = nb * 128;

    __shared__ alignas(16) bf16 As[128 * 32];
    __shared__ alignas(16) bf16 Bs[128 * 32];

    const int t = threadIdx.x;
    const int lane = t & 63, w = t >> 6;
    const bf16* Bp = Bt + (size_t)e * ND * KD;

    const int i0 = 2 * w, i1 = 2 * w + 1;
    const int ar0 = i0 * 16 + (lane >> 2);
    const int ar1 = i1 * 16 + (lane >> 2);
    const int kc = (lane & 3) * 8;

    size_t ga0, ga1;
    if (row_map) {
        ga0 = (m0 + ar0 < cnt) ? (size_t)row_map[off + m0 + ar0] : 0;
        ga1 = (m0 + ar1 < cnt) ? (size_t)row_map[off + m0 + ar1] : 0;
    } else {
        ga0 = (size_t)(off + m0 + ar0);
        ga1 = (size_t)(off + m0 + ar1);
    }
    const bf16* Ap0 = Abase + ga0 * KD + kc;
    const bf16* Ap1 = Abase + ga1 * KD + kc;
    const bf16* Bq0 = Bp + (size_t)(n0 + ar0) * KD + kc;
    const bf16* Bq1 = Bp + (size_t)(n0 + ar1) * KD + kc;

    bf16* lA0 = As + i0 * 512;
    bf16* lA1 = As + i1 * 512;
    bf16* lB0 = Bs + i0 * 512;
    bf16* lB1 = Bs + i1 * 512;

    const int wm = (w >> 1) * 64, wn = (w & 1) * 64;
    const int q = lane >> 4, c16 = lane & 15;

    float4v acc[4][4];
#pragma unroll
    for (int mi = 0; mi < 4; mi++)
#pragma unroll
        for (int ni = 0; ni < 4; ni++) acc[mi][ni] = (float4v){0.f, 0.f, 0.f, 0.f};

    for (int k0 = 0; k0 < KD; k0 += 32) {
        ASYNC_CP16(Ap0 + k0, lA0);
        ASYNC_CP16(Ap1 + k0, lA1);
        ASYNC_CP16(Bq0 + k0, lB0);
        ASYNC_CP16(Bq1 + k0, lB1);
        __syncthreads();
        short8 af[4], bfr[4];
#pragma unroll
        for (int mi = 0; mi < 4; mi++)
            af[mi] = *(const short8*)&As[(wm + mi * 16 + c16) * 32 + q * 8];
#pragma unroll
        for (int ni = 0; ni < 4; ni++)
            bfr[ni] = *(const short8*)&Bs[(wn + ni * 16 + c16) * 32 + q * 8];
#pragma unroll
        for (int mi = 0; mi < 4; mi++)
#pragma unroll
            for (int ni = 0; ni < 4; ni++)
                acc[mi][ni] = __builtin_amdgcn_mfma_f32_16x16x32_bf16(
                    af[mi], bfr[ni], acc[mi][ni], 0, 0, 0);
        __syncthreads();
    }

#pragma unroll
    for (int mi = 0; mi < 4; mi++)
#pragma unroll
        for (int reg = 0; reg < 4; reg++) {
            int row = wm + mi * 16 + q * 4 + reg;
            if (m0 + row < cnt) {
                size_t gp = (size_t)(off + m0 + row);
                if (EPI == 0) {
#pragma unroll
                    for (int ni = 0; ni < 4; ni++) {
                        int col = n0 + wn + ni * 16 + c16;
                        Hout[gp * ND + col] = __float2bfloat16(gelu_fast(acc[mi][ni][reg]));
                    }
                } else {
                    float gt = pair_gate[gp];
#pragma unroll
                    for (int ni = 0; ni < 4; ni++) {
                        int col = n0 + wn + ni * 16 + c16;
                        Yout[gp * ND + col] = acc[mi][ni][reg] * gt;
                    }
                }
            }
        }
}

// ---------------- rmsnorm (ADD=1: also add H1n residual), in place, vectorized ----------------
template <int ADD>
__global__ void rmsnorm_k(bf16* __restrict__ H, const bf16* __restrict__ H1n,
                          const float* __restrict__ nw, const int* __restrict__ pair_expert) {
    int p = blockIdx.x;
    int t = threadIdx.x;
    bf16* row = H + (size_t)p * HDIM + t * 8;
    short8 hv = *(const short8*)row;
    float v[8];
    float ss = 0.f;
#pragma unroll
    for (int i = 0; i < 8; i++) {
        v[i] = bf2f(hv[i]);
        ss += v[i] * v[i];
    }
#pragma unroll
    for (int m = 32; m >= 1; m >>= 1) ss += __shfl_xor(ss, m, 64);
    __shared__ float s4[4];
    int wv = t >> 6, lane = t & 63;
    if (lane == 0) s4[wv] = ss;
    __syncthreads();
    ss = s4[0] + s4[1] + s4[2] + s4[3];
    float scale = rsqrtf(ss / (float)HDIM + 1e-6f);
    int e = pair_expert[p];
    const float* nr = nw + (size_t)e * HDIM + t * 8;
    float4 na = *(const float4*)nr;
    float4 nb = *(const float4*)(nr + 4);
    float nv[8] = {na.x, na.y, na.z, na.w, nb.x, nb.y, nb.z, nb.w};
    short8 res;
    short8 r8;
    if (ADD) r8 = *(const short8*)(H1n + (size_t)p * HDIM + t * 8);
#pragma unroll
    for (int i = 0; i < 8; i++) {
        float o = v[i] * scale * nv[i];
        if (ADD) o += bf2f(r8[i]);
        res[i] = f2bf(o);
    }
    *(short8*)row = res;
}

// ---------------- combine two pair outputs per token ----------------
__global__ void combine_k(const float* __restrict__ y, const int* __restrict__ pair_of,
                          float* __restrict__ out) {
    int i = blockIdx.x * 256 + threadIdx.x;
    if (i >= N_TOK * DMODEL / 4) return;
    int n = i >> 7, d4 = (i & 127) << 2;
    int p0 = pair_of[2 * n], p1 = pair_of[2 * n + 1];
    const float4 a = *(const float4*)(y + (size_t)p0 * DMODEL + d4);
    const float4 b = *(const float4*)(y + (size_t)p1 * DMODEL + d4);
    float4 r;
    r.x = a.x + b.x; r.y = a.y + b.y; r.z = a.z + b.z; r.w = a.w + b.w;
    *(float4*)(out + (size_t)n * DMODEL + d4) = r;
}

extern "C" void kernel_launch(void* const* d_in, const int* in_sizes, int n_in,
                              void* d_out, int out_size, void* d_ws, size_t ws_size,
                              hipStream_t stream) {
    const float* x  = (const float*)d_in[0];
    const float* gw = (const float*)d_in[1];
    const float* w1 = (const float*)d_in[2];
    const float* w2 = (const float*)d_in[3];
    const float* w3 = (const float*)d_in[4];
    const float* n1 = (const float*)d_in[5];
    const float* n2 = (const float*)d_in[6];
    float* out = (float*)d_out;

    char* wsp = (char*)d_ws;
    size_t cur = 0;
    auto take = [&](size_t bytes) -> void* {
        void* p = wsp + cur;
        cur += (bytes + 255) & ~(size_t)255;
        return p;
    };
    bf16* xb  = (bf16*)take((size_t)N_TOK * DMODEL * 2);
    bf16* w1t = (bf16*)take((size_t)NEXP * DMODEL * HDIM * 2);
    bf16* w2t = (bf16*)take((size_t)NEXP * HDIM * HDIM * 2);
    bf16* w3t = (bf16*)take((size_t)NEXP * HDIM * DMODEL * 2);
    bf16* h1  = (bf16*)take((size_t)PAIR_PAD * HDIM * 2);
    bf16* h2  = (bf16*)take((size_t)PAIR_PAD * HDIM * 2);
    float* y  = (float*)take((size_t)PAIR_PAD * DMODEL * 4);
    int* tok_idx     = (int*)take((size_t)NPAIR * 4);
    float* tok_gate  = (float*)take((size_t)NPAIR * 4);
    int* pair_token  = (int*)take((size_t)PAIR_PAD * 4);
    float* pair_gate = (float*)take((size_t)PAIR_PAD * 4);
    int* pair_expert = (int*)take((size_t)PAIR_PAD * 4);
    int* pair_of     = (int*)take((size_t)NPAIR * 4);
    int* blkc    = (int*)take((size_t)NGBLK * 8 * 4);
    int* blkbase = (int*)take((size_t)NGBLK * 8 * 4);
    int* offs    = (int*)take((NEXP + 1) * 4);

    cvt_x_k<<<N_TOK * DMODEL / 4 / 256, 256, 0, stream>>>(x, xb);
    gating_k<<<NGBLK, 256, 0, stream>>>(x, gw, tok_idx, tok_gate, blkc);
    scan_k<<<1, 512, 0, stream>>>(blkc, blkbase, offs);
    place_k<<<NPAIR / 256, 256, 0, stream>>>(tok_idx, tok_gate, blkbase,
                                             pair_token, pair_gate, pair_expert, pair_of);

    transpose_all_k<<<NEXP * 1536, 256, 0, stream>>>(w1, w2, w3, w1t, w2t, w3t);

    // stage 1: h1 = gelu(x @ w1)   (256x256; 1D grid, XCD-chunked: e=bid&7)
    gemm256_k<DMODEL, HDIM, 0><<<NEXP * 64 * (HDIM / 256), 512, 0, stream>>>(
        xb, w1t, pair_token, offs, h1, nullptr, nullptr);
    rmsnorm_k<0><<<NPAIR, 256, 0, stream>>>(h1, nullptr, n1, pair_expert);

    // stage 2: h2 = gelu(h1n @ w2)
    gemm256_k<HDIM, HDIM, 0><<<NEXP * 64 * (HDIM / 256), 512, 0, stream>>>(
        h1, w2t, nullptr, offs, h2, nullptr, nullptr);
    rmsnorm_k<1><<<NPAIR, 256, 0, stream>>>(h2, h1, n2, pair_expert);

    // stage 3: y = gate * ((h2n + h1n) @ w3)  (128x128; 1D grid, XCD-chunked)
    gemm_moe_k<HDIM, DMODEL, 1><<<NEXP * 64 * (DMODEL / 128), 256, 0, stream>>>(
        h2, w3t, nullptr, offs, nullptr, y, pair_gate);

    combine_k<<<N_TOK * DMODEL / 4 / 256, 256, 0, stream>>>(y, pair_of, out);
}